// Round 10
// baseline (208.526 us; speedup 1.0000x reference)
//
#include <hip/hip_runtime.h>
#include <hip/hip_bf16.h>

#define BATCH 8
#define NC 2048
#define NF 8192
#define CDIM 256
#define CSKIP 64
#define OUTD 256
#define MTOT (BATCH*NF)   // 65536
#define NCTOT (BATCH*NC)  // 16384
#define KCH4 512          // per-wave coarse chunk (4-way split)

typedef __attribute__((ext_vector_type(8))) short short8;
typedef __attribute__((ext_vector_type(4))) float floatx4;

static __device__ __forceinline__ ushort f2bf(float f) {
    union { float f; unsigned u; } v; v.f = f;
    unsigned r = v.u + 0x7fffu + ((v.u >> 16) & 1u);   // RNE
    return (ushort)(r >> 16);
}
static __device__ __forceinline__ float bf2f(ushort u) {
    union { unsigned u; float f; } v; v.u = ((unsigned)u) << 16;
    return v.f;
}

#if defined(__has_builtin) && __has_builtin(__builtin_amdgcn_fmed3f)
#define MED3F(a, b, c) __builtin_amdgcn_fmed3f((a), (b), (c))
#else
static __device__ __forceinline__ float MED3F(float a, float b, float c) {
    return fmaxf(fminf(a, b), fminf(fmaxf(a, b), c));
}
#endif

// branchless strict-< top-3 insert, parametrized state (exact jax top_k tie order
// when fed ascending j)
#define TOP3_INS(d, jj, D0, D1, D2, I0, I1, I2)     \
    {                                               \
        bool c2 = (d) < D2, c1 = (d) < D1, c0 = (d) < D0; \
        I2 = c1 ? I1 : (c2 ? (jj) : I2);            \
        I1 = c0 ? I0 : (c1 ? (jj) : I1);            \
        I0 = c0 ? (jj) : I0;                        \
        D2 = MED3F(D1, D2, (d));                    \
        D1 = MED3F(D0, D1, (d));                    \
        D0 = fminf(D0, (d));                        \
    }

// ---- kernel 1: prep_all = prep_w (blocks 0..35) + prep (blocks 36..).
#define SEG0 1048576   // x -> xb bf16 (float4-wide)
#define SEG1 1048576   // x_skip -> xsb bf16
#define SEG5 16384     // pos -> pos4
#define SEG6 (MTOT*3)  // pos_skip -> out tail
#define SEG7 MTOT      // batch ids -> out tail
#define PREP_THREADS (SEG0+SEG1+SEG5+SEG6+SEG7)
#define PW_BLOCKS 36
#define PREP_BLOCKS (PW_BLOCKS + (PREP_THREADS + 255) / 256)

__global__ __launch_bounds__(256) void prep_all(const float* __restrict__ x,
                                                const float* __restrict__ x_skip,
                                                const float* __restrict__ pos,
                                                const float* __restrict__ pos_skip,
                                                const float* __restrict__ W1,
                                                const float* __restrict__ W2,
                                                ushort* __restrict__ xb,
                                                ushort* __restrict__ xsb,
                                                float4* __restrict__ pos4,
                                                ushort* __restrict__ Bt1a,
                                                ushort* __restrict__ Bt1b,
                                                ushort* __restrict__ Bt2,
                                                float* __restrict__ out) {
    __shared__ ushort tile[64 * 65];
    if (blockIdx.x < PW_BLOCKS) {
        // ---- weight transpose (64x64 LDS tiles, pad 65)
        int bid = blockIdx.x;
        const float* src; ushort* dst; int k0, n0, KD;
        if (bid < 16)      { src = W1;             dst = Bt1a; k0 = (bid >> 2) * 64; n0 = (bid & 3) * 64; KD = 256; }
        else if (bid < 20) { src = W1 + 256 * 256; dst = Bt1b; k0 = 0;               n0 = (bid - 16) * 64; KD = 64; }
        else               { int b2 = bid - 20; src = W2; dst = Bt2; k0 = (b2 >> 2) * 64; n0 = (b2 & 3) * 64; KD = 256; }
        int tx = threadIdx.x & 63, ty = threadIdx.x >> 6;
#pragma unroll
        for (int r = 0; r < 64; r += 4) {
            int k = r + ty;
            tile[k * 65 + tx] = f2bf(src[(size_t)(k0 + k) * 256 + n0 + tx]);
        }
        __syncthreads();
#pragma unroll
        for (int r = 0; r < 64; r += 4) {
            int n = r + ty;
            dst[(size_t)(n0 + n) * KD + k0 + tx] = tile[tx * 65 + n];
        }
        return;
    }
    int t = (blockIdx.x - PW_BLOCKS) * 256 + threadIdx.x;
    if (t < SEG0) {
        float4 v = ((const float4*)x)[t];
        ushort4 p; p.x = f2bf(v.x); p.y = f2bf(v.y); p.z = f2bf(v.z); p.w = f2bf(v.w);
        ((ushort4*)xb)[t] = p;
        return;
    }
    t -= SEG0;
    if (t < SEG1) {
        float4 v = ((const float4*)x_skip)[t];
        ushort4 p; p.x = f2bf(v.x); p.y = f2bf(v.y); p.z = f2bf(v.z); p.w = f2bf(v.w);
        ((ushort4*)xsb)[t] = p;
        return;
    }
    t -= SEG1;
    if (t < SEG5) {
        float4 q;
        q.x = pos[t * 3 + 0]; q.y = pos[t * 3 + 1]; q.z = pos[t * 3 + 2]; q.w = 0.f;
        pos4[t] = q;
        return;
    }
    t -= SEG5;
    if (t < SEG6) {
        out[(size_t)MTOT * OUTD + t] = pos_skip[t];
        return;
    }
    t -= SEG6;
    if (t < SEG7) {
        out[(size_t)MTOT * OUTD + (size_t)MTOT * 3 + t] = (float)(t >> 13);
    }
}

// ---- kernel 2: knn_gemm — heterogeneous dispatch, LDS union shrunk to the
// knn footprint (29.3 KB) by half-staging the gemm's B panel (128 N-rows per
// phase instead of 256). Round-9 showed the 36 KB union capped residency at
// 4 blocks/CU; VGPR=60 allows 8, so LDS was binding. 29.3 KB -> 5 blocks/CU
// = 5 waves/SIMD for the knn blocks (r8->r9 established issue rate tracks
// waves/SIMD: 2->4 gave 69->86% VALUBusy). Cost: 2x barriers + af re-read
// in the gemm blocks only (~256 blocks, overlapped anyway).
#define GW_STRIDE 72
#define KNN_BASE 256
#define KNN_LDS 29696
__global__ __launch_bounds__(256, 4) void knn_gemm(const float4* __restrict__ pos4,
                                                   const float* __restrict__ pos_skip,
                                                   int* __restrict__ idxw,
                                                   float* __restrict__ wgt,
                                                   const ushort* __restrict__ A,
                                                   const ushort* __restrict__ Bt,
                                                   ushort* __restrict__ Gb) {
    __shared__ __align__(16) char smem[KNN_LDS];
    int tid = threadIdx.x;
    int wave = tid >> 6;
    int lane = tid & 63;

    if (blockIdx.x < KNN_BASE) {
        // ======== gemm_G: Gb = bf16( xb @ Bt1a^T ), half-staged B panel ======
        ushort* wB = (ushort*)smem;                    // 128*72 ushort = 18.4 KB
        int m0 = blockIdx.x * 64 + wave * 16;
        int lrow = lane & 15;
        int ko = (lane >> 4) * 8;

        floatx4 acc[16];
#pragma unroll
        for (int i = 0; i < 16; ++i) acc[i] = (floatx4){0.f, 0.f, 0.f, 0.f};

        for (int s = 0; s < 4; ++s) {
#pragma unroll
            for (int hh = 0; hh < 2; ++hh) {
                if (s || hh) __syncthreads();
                for (int cch = tid; cch < 1024; cch += 256) {
                    int n = cch >> 3, koff = (cch & 7) * 8;
                    *(short8*)&wB[n * GW_STRIDE + koff] =
                        *(const short8*)(Bt + (size_t)(hh * 128 + n) * 256 + s * 64 + koff);
                }
                __syncthreads();
                const ushort* ar = A + (size_t)(m0 + lrow) * 256 + s * 64 + ko;
#pragma unroll
                for (int k0 = 0; k0 < 64; k0 += 32) {
                    short8 af = *(const short8*)(ar + k0);
#pragma unroll
                    for (int ntl = 0; ntl < 8; ++ntl) {
                        short8 bf = *(const short8*)&wB[(ntl * 16 + lrow) * GW_STRIDE + k0 + ko];
                        acc[hh * 8 + ntl] = __builtin_amdgcn_mfma_f32_16x16x32_bf16(af, bf, acc[hh * 8 + ntl], 0, 0, 0);
                    }
                }
            }
        }
        int rbase = (lane >> 4) * 4;
#pragma unroll
        for (int nt = 0; nt < 16; ++nt) {
            int n = nt * 16 + lrow;
#pragma unroll
            for (int r = 0; r < 4; ++r)
                Gb[(size_t)(m0 + rbase + r) * 256 + n] = f2bf(acc[nt][r]);
        }
        return;
    }

    // ================= knn (r8 structure, verbatim semantics) =================
    float* sx = (float*)smem;                      // NC+8
    float* sy = sx + (NC + 8);
    float* sz = sy + (NC + 8);
    float* pd = sz + (NC + 8);                     // 3*192 floats
    int*   pi = (int*)(pd + 3 * 192);              // 3*192 ints  (total 29280 B)

    int kb = blockIdx.x - KNN_BASE;
    int m = kb * 64 + lane;         // all 4 waves: same 64 fine points
    int b = m >> 13;                // whole block inside one cloud
    int jbase = b * NC;

    for (int i = tid; i < NC; i += 256) {
        float4 q = pos4[jbase + i];
        sx[i] = q.x; sy[i] = q.y; sz[i] = q.z;
    }
    float px = pos_skip[m * 3 + 0];
    float py = pos_skip[m * 3 + 1];
    float pz = pos_skip[m * 3 + 2];
    __syncthreads();

    int joff = wave * KCH4;

    float d0 = 1e30f, d1 = 1e30f, d2 = 1e30f;
    int i0 = jbase, i1 = jbase, i2 = jbase;

    // preload window 0 (local j 0..7) into A registers
    float4 ax0 = *(const float4*)&sx[joff],     ax1 = *(const float4*)&sx[joff + 4];
    float4 ay0 = *(const float4*)&sy[joff],     ay1 = *(const float4*)&sy[joff + 4];
    float4 az0 = *(const float4*)&sz[joff],     az1 = *(const float4*)&sz[joff + 4];

    for (int j16 = 0; j16 < KCH4; j16 += 16) {
        // issue prefetch of window B (local j16+8 .. j16+15)
        int jb2 = joff + j16 + 8;
        float4 bx0 = *(const float4*)&sx[jb2],     bx1 = *(const float4*)&sx[jb2 + 4];
        float4 by0 = *(const float4*)&sy[jb2],     by1 = *(const float4*)&sy[jb2 + 4];
        float4 bz0 = *(const float4*)&sz[jb2],     bz1 = *(const float4*)&sz[jb2 + 4];

        // compute + insert window A (j16 .. j16+7) — hides B's LDS latency
        {
            float dd[8];
#pragma unroll
            for (int u = 0; u < 4; ++u) {
                float ax = px - ax0[u], ay = py - ay0[u], az = pz - az0[u];
                dd[u] = ax * ax + ay * ay + az * az;
                float bx = px - ax1[u], by = py - ay1[u], bz = pz - az1[u];
                dd[u + 4] = bx * bx + by * by + bz * bz;
            }
#pragma unroll
            for (int u = 0; u < 8; ++u) {
                if (__any(dd[u] < d2)) {
                    int jj = jbase + joff + j16 + u;
                    TOP3_INS(dd[u], jj, d0, d1, d2, i0, i1, i2);
                }
            }
        }

        // issue prefetch of next window A (local j16+16 .. j16+23).
        // Last iteration of wave 3 reads into the +8 pad; values are dead.
        int jn = joff + j16 + 16;
        ax0 = *(const float4*)&sx[jn];     ax1 = *(const float4*)&sx[jn + 4];
        ay0 = *(const float4*)&sy[jn];     ay1 = *(const float4*)&sy[jn + 4];
        az0 = *(const float4*)&sz[jn];     az1 = *(const float4*)&sz[jn + 4];

        // compute + insert window B (j16+8 .. j16+15)
        {
            float dd[8];
#pragma unroll
            for (int u = 0; u < 4; ++u) {
                float ax = px - bx0[u], ay = py - by0[u], az = pz - bz0[u];
                dd[u] = ax * ax + ay * ay + az * az;
                float bx = px - bx1[u], by = py - by1[u], bz = pz - bz1[u];
                dd[u + 4] = bx * bx + by * by + bz * bz;
            }
#pragma unroll
            for (int u = 0; u < 8; ++u) {
                if (__any(dd[u] < d2)) {
                    int jj = jbase + joff + j16 + 8 + u;
                    TOP3_INS(dd[u], jj, d0, d1, d2, i0, i1, i2);
                }
            }
        }
    }

    if (wave) {
        pd[(wave - 1) * 192 + lane * 3 + 0] = d0;
        pd[(wave - 1) * 192 + lane * 3 + 1] = d1;
        pd[(wave - 1) * 192 + lane * 3 + 2] = d2;
        pi[(wave - 1) * 192 + lane * 3 + 0] = i0;
        pi[(wave - 1) * 192 + lane * 3 + 1] = i1;
        pi[(wave - 1) * 192 + lane * 3 + 2] = i2;
    }
    __syncthreads();
    if (wave == 0) {
        // merge chunk 1..3 partials in chunk order -> jax top_k order.
#pragma unroll
        for (int c = 0; c < 3; ++c) {
#pragma unroll
            for (int s = 0; s < 3; ++s) {
                float d = pd[c * 192 + lane * 3 + s];
                int jj = pi[c * 192 + lane * 3 + s];
                TOP3_INS(d, jj, d0, d1, d2, i0, i1, i2);
            }
        }
        float w0 = 1.0f / fmaxf(d0, 1e-16f);
        float w1 = 1.0f / fmaxf(d1, 1e-16f);
        float w2 = 1.0f / fmaxf(d2, 1e-16f);
        float inv = 1.0f / (w0 + w1 + w2);
        idxw[m * 3 + 0] = i0;  wgt[m * 3 + 0] = w0 * inv;
        idxw[m * 3 + 1] = i1;  wgt[m * 3 + 1] = w1 * inv;
        idxw[m * 3 + 2] = i2;  wgt[m * 3 + 2] = w2 * inv;
    }
}

// ---- kernel 3: fused  h1 = relu(x_skip@W1b + interp(Gb) + b1);  out = relu(h1@W2 + b2)
// Round-10 change: wB half-staged (128 N-rows/phase) -> LDS 72 KB -> 53.8 KB
// -> 3 blocks/CU (was 2). launch_bounds(256,3) caps VGPR ~170 (est use ~130).
#define LDS_STRIDE 264
#define WB_STRIDE 72
__global__ __launch_bounds__(256, 3) void fused_kernel(const ushort* __restrict__ xsb,
                                                       const ushort* __restrict__ Bt1b,
                                                       const ushort* __restrict__ Gb,
                                                       const int* __restrict__ idxw,
                                                       const float* __restrict__ wgt,
                                                       const float* __restrict__ b1,
                                                       const ushort* __restrict__ Bt2,
                                                       const float* __restrict__ b2,
                                                       float* __restrict__ out) {
    __shared__ ushort h1t[4][16 * LDS_STRIDE];     // 33792 B
    __shared__ ushort wB[128 * WB_STRIDE];         // 18432 B
    __shared__ int   sIdx[4][48];
    __shared__ float sWgt[4][48];                  // total 53760 B -> 3 blk/CU
    int tid = threadIdx.x;
    int wave = tid >> 6, lane = tid & 63;
    int m0 = blockIdx.x * 64 + wave * 16;
    int lrow = lane & 15;
    int ko = (lane >> 4) * 8;
    int rbase = (lane >> 4) * 4;

    if (lane < 48) {
        sIdx[wave][lane] = idxw[m0 * 3 + lane];
        sWgt[wave][lane] = wgt[m0 * 3 + lane];
    }

    const ushort4* Gv = (const ushort4*)Gb;
    const int*   si = sIdx[wave];
    const float* sw = sWgt[wave];
    ushort4 g[4][3];
#define GATHER(slot, i) {                                         \
        int a0 = si[(i) * 3 + 0];                                 \
        int a1 = si[(i) * 3 + 1];                                 \
        int a2 = si[(i) * 3 + 2];                                 \
        g[slot][0] = Gv[(size_t)a0 * 64 + lane];                  \
        g[slot][1] = Gv[(size_t)a1 * 64 + lane];                  \
        g[slot][2] = Gv[(size_t)a2 * 64 + lane]; }

    GATHER(0, 0) GATHER(1, 1) GATHER(2, 2) GATHER(3, 3)

    floatx4 acc[16];
#pragma unroll
    for (int i = 0; i < 16; ++i) acc[i] = (floatx4){0.f, 0.f, 0.f, 0.f};

    // gemm1: x_skip @ W1b, half-staged B panel (Bt1b is 256 x 64)
#pragma unroll
    for (int hh = 0; hh < 2; ++hh) {
        if (hh) __syncthreads();
        for (int cch = tid; cch < 1024; cch += 256) {
            int n = cch >> 3, koff = (cch & 7) * 8;
            *(short8*)&wB[n * WB_STRIDE + koff] =
                *(const short8*)(Bt1b + (size_t)(hh * 128 + n) * 64 + koff);
        }
        __syncthreads();
        const ushort* arow = xsb + (size_t)(m0 + lrow) * 64 + ko;
#pragma unroll
        for (int k0 = 0; k0 < 64; k0 += 32) {
            short8 af = *(const short8*)(arow + k0);
#pragma unroll
            for (int ntl = 0; ntl < 8; ++ntl) {
                short8 bf = *(const short8*)&wB[(ntl * 16 + lrow) * WB_STRIDE + k0 + ko];
                acc[hh * 8 + ntl] = __builtin_amdgcn_mfma_f32_16x16x32_bf16(af, bf, acc[hh * 8 + ntl], 0, 0, 0);
            }
        }
    }

    ushort* ht = h1t[wave];
#pragma unroll
    for (int nt = 0; nt < 16; ++nt) {
        int n = nt * 16 + lrow;
#pragma unroll
        for (int r = 0; r < 4; ++r)
            ht[(rbase + r) * LDS_STRIDE + n] = f2bf(acc[nt][r]);
    }

    {
        float4 bv = ((const float4*)b1)[lane];
#define COMBINE(i) {                                              \
        int s = (i) & 3;                                          \
        float w0 = sw[(i) * 3 + 0], w1 = sw[(i) * 3 + 1], w2 = sw[(i) * 3 + 2]; \
        ushort4 sv = *(const ushort4*)(ht + (i) * LDS_STRIDE + 4 * lane); \
        float4 h;                                                 \
        h.x = fmaxf(bf2f(sv.x) + w0 * bf2f(g[s][0].x) + w1 * bf2f(g[s][1].x) + w2 * bf2f(g[s][2].x) + bv.x, 0.f); \
        h.y = fmaxf(bf2f(sv.y) + w0 * bf2f(g[s][0].y) + w1 * bf2f(g[s][1].y) + w2 * bf2f(g[s][2].y) + bv.y, 0.f); \
        h.z = fmaxf(bf2f(sv.z) + w0 * bf2f(g[s][0].z) + w1 * bf2f(g[s][1].z) + w2 * bf2f(g[s][2].z) + bv.z, 0.f); \
        h.w = fmaxf(bf2f(sv.w) + w0 * bf2f(g[s][0].w) + w1 * bf2f(g[s][1].w) + w2 * bf2f(g[s][2].w) + bv.w, 0.f); \
        ushort4 hp;                                               \
        hp.x = f2bf(h.x); hp.y = f2bf(h.y); hp.z = f2bf(h.z); hp.w = f2bf(h.w); \
        *(ushort4*)(ht + (i) * LDS_STRIDE + 4 * lane) = hp; }

#pragma unroll
        for (int i = 0; i < 12; ++i) { COMBINE(i); GATHER(i & 3, i + 4); }
#pragma unroll
        for (int i = 12; i < 16; ++i) { COMBINE(i); }
#undef GATHER
#undef COMBINE
    }

#pragma unroll
    for (int i = 0; i < 16; ++i) acc[i] = (floatx4){0.f, 0.f, 0.f, 0.f};
    // gemm2: h1 @ W2, half-staged B panel per k-slice
    for (int s = 0; s < 4; ++s) {
#pragma unroll
        for (int hh = 0; hh < 2; ++hh) {
            __syncthreads();
            for (int cch = tid; cch < 1024; cch += 256) {
                int n = cch >> 3, koff = (cch & 7) * 8;
                *(short8*)&wB[n * WB_STRIDE + koff] =
                    *(const short8*)(Bt2 + (size_t)(hh * 128 + n) * 256 + s * 64 + koff);
            }
            __syncthreads();
            const ushort* ar = ht + lrow * LDS_STRIDE + s * 64 + ko;
#pragma unroll
            for (int k0 = 0; k0 < 64; k0 += 32) {
                short8 af = *(const short8*)(ar + k0);
#pragma unroll
                for (int ntl = 0; ntl < 8; ++ntl) {
                    short8 bf = *(const short8*)&wB[(ntl * 16 + lrow) * WB_STRIDE + k0 + ko];
                    acc[hh * 8 + ntl] = __builtin_amdgcn_mfma_f32_16x16x32_bf16(af, bf, acc[hh * 8 + ntl], 0, 0, 0);
                }
            }
        }
    }
#pragma unroll
    for (int nt = 0; nt < 16; ++nt) {
        int n = nt * 16 + lrow;
        float bv2 = b2[n];
#pragma unroll
        for (int r = 0; r < 4; ++r) {
            float v = fmaxf(acc[nt][r] + bv2, 0.f);
            out[(size_t)(m0 + rbase + r) * OUTD + n] = v;
        }
    }
}

extern "C" void kernel_launch(void* const* d_in, const int* in_sizes, int n_in,
                              void* d_out, int out_size, void* d_ws, size_t ws_size,
                              hipStream_t stream) {
    const float* x        = (const float*)d_in[0];
    const float* pos      = (const float*)d_in[1];
    const float* x_skip   = (const float*)d_in[3];
    const float* pos_skip = (const float*)d_in[4];
    const float* W1       = (const float*)d_in[6];
    const float* b1       = (const float*)d_in[7];
    const float* W2       = (const float*)d_in[8];
    const float* b2       = (const float*)d_in[9];

    char* ws = (char*)d_ws;
    size_t off = 0;
    int*    idxw = (int*)(ws + off);    off += (size_t)MTOT * 3 * 4;      //  768 KB
    float*  wgt  = (float*)(ws + off);  off += (size_t)MTOT * 3 * 4;      //  768 KB
    ushort* xb   = (ushort*)(ws + off); off += (size_t)NCTOT * 256 * 2;   //    8 MB
    ushort* xsb  = (ushort*)(ws + off); off += (size_t)MTOT * 64 * 2;     //    8 MB
    ushort* Gb   = (ushort*)(ws + off); off += (size_t)NCTOT * 256 * 2;   //    8 MB
    ushort* Bt1a = (ushort*)(ws + off); off += (size_t)256 * 256 * 2;     //  128 KB
    ushort* Bt1b = (ushort*)(ws + off); off += (size_t)256 * 64 * 2;      //   32 KB
    ushort* Bt2  = (ushort*)(ws + off); off += (size_t)256 * 256 * 2;     //  128 KB
    float4* pos4 = (float4*)(ws + off); off += (size_t)(NCTOT + 8) * 16;  //  256 KB
    float* out = (float*)d_out;

    prep_all<<<PREP_BLOCKS, 256, 0, stream>>>(
        x, x_skip, pos, pos_skip, W1, W2, xb, xsb, pos4, Bt1a, Bt1b, Bt2, out);
    knn_gemm<<<KNN_BASE + MTOT / 64, 256, 0, stream>>>(
        pos4, pos_skip, idxw, wgt, xb, Bt1a, Gb);
    fused_kernel<<<MTOT / 64, 256, 0, stream>>>(xsb, Bt1b, Gb, idxw, wgt, b1, Bt2, b2, out);
}

// Round 11
// 196.018 us; speedup vs baseline: 1.0638x; 1.0638x over previous
//
#include <hip/hip_runtime.h>
#include <hip/hip_bf16.h>

#define BATCH 8
#define NC 2048
#define NF 8192
#define CDIM 256
#define CSKIP 64
#define OUTD 256
#define MTOT (BATCH*NF)   // 65536
#define NCTOT (BATCH*NC)  // 16384
#define KCH4 512          // per-wave coarse chunk (4-way split)

typedef __attribute__((ext_vector_type(8))) short short8;
typedef __attribute__((ext_vector_type(4))) float floatx4;

static __device__ __forceinline__ ushort f2bf(float f) {
    union { float f; unsigned u; } v; v.f = f;
    unsigned r = v.u + 0x7fffu + ((v.u >> 16) & 1u);   // RNE
    return (ushort)(r >> 16);
}
static __device__ __forceinline__ float bf2f(ushort u) {
    union { unsigned u; float f; } v; v.u = ((unsigned)u) << 16;
    return v.f;
}
// load 8 f32 and convert to a bf16 short8 fragment (bit-identical to the
// old prep-cast + bf16 reload path; the cast is just fused into the consumer)
static __device__ __forceinline__ short8 ld_cvt8(const float* __restrict__ p) {
    float4 a = *(const float4*)p;
    float4 b = *(const float4*)(p + 4);
    short8 r;
    r[0] = (short)f2bf(a.x); r[1] = (short)f2bf(a.y);
    r[2] = (short)f2bf(a.z); r[3] = (short)f2bf(a.w);
    r[4] = (short)f2bf(b.x); r[5] = (short)f2bf(b.y);
    r[6] = (short)f2bf(b.z); r[7] = (short)f2bf(b.w);
    return r;
}

#if defined(__has_builtin) && __has_builtin(__builtin_amdgcn_fmed3f)
#define MED3F(a, b, c) __builtin_amdgcn_fmed3f((a), (b), (c))
#else
static __device__ __forceinline__ float MED3F(float a, float b, float c) {
    return fmaxf(fminf(a, b), fminf(fmaxf(a, b), c));
}
#endif

// branchless strict-< top-3 insert, parametrized state (exact jax top_k tie order
// when fed ascending j)
#define TOP3_INS(d, jj, D0, D1, D2, I0, I1, I2)     \
    {                                               \
        bool c2 = (d) < D2, c1 = (d) < D1, c0 = (d) < D0; \
        I2 = c1 ? I1 : (c2 ? (jj) : I2);            \
        I1 = c0 ? I0 : (c1 ? (jj) : I1);            \
        I0 = c0 ? (jj) : I0;                        \
        D2 = MED3F(D1, D2, (d));                    \
        D1 = MED3F(D0, D1, (d));                    \
        D0 = fminf(D0, (d));                        \
    }

// ---- kernel 1: prep_all = weight transpose (blocks 0..35) + pos4/out-tail.
// Round-11: x->xb and x_skip->xsb casts DELETED — consumers read f32 and
// convert inline (ld_cvt8), removing 49 MB of prep traffic and the 16 MB
// bf16 intermediate round-trip.
#define SEG5 16384     // pos -> pos4
#define SEG6 (MTOT*3)  // pos_skip -> out tail
#define SEG7 MTOT      // batch ids -> out tail
#define PREP_THREADS (SEG5+SEG6+SEG7)
#define PW_BLOCKS 36
#define PREP_BLOCKS (PW_BLOCKS + (PREP_THREADS + 255) / 256)

__global__ __launch_bounds__(256) void prep_all(const float* __restrict__ pos,
                                                const float* __restrict__ pos_skip,
                                                const float* __restrict__ W1,
                                                const float* __restrict__ W2,
                                                float4* __restrict__ pos4,
                                                ushort* __restrict__ Bt1a,
                                                ushort* __restrict__ Bt1b,
                                                ushort* __restrict__ Bt2,
                                                float* __restrict__ out) {
    __shared__ ushort tile[64 * 65];
    if (blockIdx.x < PW_BLOCKS) {
        // ---- weight transpose (64x64 LDS tiles, pad 65)
        int bid = blockIdx.x;
        const float* src; ushort* dst; int k0, n0, KD;
        if (bid < 16)      { src = W1;             dst = Bt1a; k0 = (bid >> 2) * 64; n0 = (bid & 3) * 64; KD = 256; }
        else if (bid < 20) { src = W1 + 256 * 256; dst = Bt1b; k0 = 0;               n0 = (bid - 16) * 64; KD = 64; }
        else               { int b2 = bid - 20; src = W2; dst = Bt2; k0 = (b2 >> 2) * 64; n0 = (b2 & 3) * 64; KD = 256; }
        int tx = threadIdx.x & 63, ty = threadIdx.x >> 6;
#pragma unroll
        for (int r = 0; r < 64; r += 4) {
            int k = r + ty;
            tile[k * 65 + tx] = f2bf(src[(size_t)(k0 + k) * 256 + n0 + tx]);
        }
        __syncthreads();
#pragma unroll
        for (int r = 0; r < 64; r += 4) {
            int n = r + ty;
            dst[(size_t)(n0 + n) * KD + k0 + tx] = tile[tx * 65 + n];
        }
        return;
    }
    int t = (blockIdx.x - PW_BLOCKS) * 256 + threadIdx.x;
    if (t < SEG5) {
        float4 q;
        q.x = pos[t * 3 + 0]; q.y = pos[t * 3 + 1]; q.z = pos[t * 3 + 2]; q.w = 0.f;
        pos4[t] = q;
        return;
    }
    t -= SEG5;
    if (t < SEG6) {
        out[(size_t)MTOT * OUTD + t] = pos_skip[t];
        return;
    }
    t -= SEG6;
    if (t < SEG7) {
        out[(size_t)MTOT * OUTD + (size_t)MTOT * 3 + t] = (float)(t >> 13);
    }
}

// ---- kernel 2: knn_gemm — heterogeneous dispatch (r9 structure, best
// measured 64.0us inside 199.8 total). blocks 0..255 = gemm (A read f32 +
// inline cvt — round-11 change), blocks 256..1279 = knn (r8 loop verbatim,
// at its measured issue ceiling ~85%). 36 KB LDS union, 4 blk/CU.
#define GW_STRIDE 72
#define KNN_BASE 256
__global__ __launch_bounds__(256, 4) void knn_gemm(const float4* __restrict__ pos4,
                                                   const float* __restrict__ pos_skip,
                                                   int* __restrict__ idxw,
                                                   float* __restrict__ wgt,
                                                   const float* __restrict__ X,
                                                   const ushort* __restrict__ Bt,
                                                   ushort* __restrict__ Gb) {
    __shared__ __align__(16) char smem[36864];
    int tid = threadIdx.x;
    int wave = tid >> 6;
    int lane = tid & 63;

    if (blockIdx.x < KNN_BASE) {
        // ====== gemm_G: Gb = bf16( bf16(x) @ Bt1a^T ), A cast inline ======
        ushort* wB = (ushort*)smem;                    // 256*72 ushort = 36 KB
        int m0 = blockIdx.x * 64 + wave * 16;
        int lrow = lane & 15;
        int ko = (lane >> 4) * 8;

        floatx4 acc[16];
#pragma unroll
        for (int i = 0; i < 16; ++i) acc[i] = (floatx4){0.f, 0.f, 0.f, 0.f};

        for (int s = 0; s < 4; ++s) {
            if (s) __syncthreads();
            for (int cch = tid; cch < 2048; cch += 256) {
                int n = cch >> 3, koff = (cch & 7) * 8;
                *(short8*)&wB[n * GW_STRIDE + koff] = *(const short8*)(Bt + n * 256 + s * 64 + koff);
            }
            __syncthreads();
            const float* ar = X + (size_t)(m0 + lrow) * 256 + s * 64 + ko;
#pragma unroll
            for (int k0 = 0; k0 < 64; k0 += 32) {
                short8 af = ld_cvt8(ar + k0);
#pragma unroll
                for (int nt = 0; nt < 16; ++nt) {
                    short8 bf = *(const short8*)&wB[(nt * 16 + lrow) * GW_STRIDE + k0 + ko];
                    acc[nt] = __builtin_amdgcn_mfma_f32_16x16x32_bf16(af, bf, acc[nt], 0, 0, 0);
                }
            }
        }
        int rbase = (lane >> 4) * 4;
#pragma unroll
        for (int nt = 0; nt < 16; ++nt) {
            int n = nt * 16 + lrow;
#pragma unroll
            for (int r = 0; r < 4; ++r)
                Gb[(size_t)(m0 + rbase + r) * 256 + n] = f2bf(acc[nt][r]);
        }
        return;
    }

    // ================= knn (r8 structure, verbatim semantics) =================
    float* sx = (float*)smem;                      // NC+8
    float* sy = sx + (NC + 8);
    float* sz = sy + (NC + 8);
    float* pd = sz + (NC + 8);                     // 3*192 floats
    int*   pi = (int*)(pd + 3 * 192);              // 3*192 ints  (total 29280 B)

    int kb = blockIdx.x - KNN_BASE;
    int m = kb * 64 + lane;         // all 4 waves: same 64 fine points
    int b = m >> 13;                // whole block inside one cloud
    int jbase = b * NC;

    for (int i = tid; i < NC; i += 256) {
        float4 q = pos4[jbase + i];
        sx[i] = q.x; sy[i] = q.y; sz[i] = q.z;
    }
    float px = pos_skip[m * 3 + 0];
    float py = pos_skip[m * 3 + 1];
    float pz = pos_skip[m * 3 + 2];
    __syncthreads();

    int joff = wave * KCH4;

    float d0 = 1e30f, d1 = 1e30f, d2 = 1e30f;
    int i0 = jbase, i1 = jbase, i2 = jbase;

    // preload window 0 (local j 0..7) into A registers
    float4 ax0 = *(const float4*)&sx[joff],     ax1 = *(const float4*)&sx[joff + 4];
    float4 ay0 = *(const float4*)&sy[joff],     ay1 = *(const float4*)&sy[joff + 4];
    float4 az0 = *(const float4*)&sz[joff],     az1 = *(const float4*)&sz[joff + 4];

    for (int j16 = 0; j16 < KCH4; j16 += 16) {
        // issue prefetch of window B (local j16+8 .. j16+15)
        int jb2 = joff + j16 + 8;
        float4 bx0 = *(const float4*)&sx[jb2],     bx1 = *(const float4*)&sx[jb2 + 4];
        float4 by0 = *(const float4*)&sy[jb2],     by1 = *(const float4*)&sy[jb2 + 4];
        float4 bz0 = *(const float4*)&sz[jb2],     bz1 = *(const float4*)&sz[jb2 + 4];

        // compute + insert window A (j16 .. j16+7) — hides B's LDS latency
        {
            float dd[8];
#pragma unroll
            for (int u = 0; u < 4; ++u) {
                float ax = px - ax0[u], ay = py - ay0[u], az = pz - az0[u];
                dd[u] = ax * ax + ay * ay + az * az;
                float bx = px - ax1[u], by = py - ay1[u], bz = pz - az1[u];
                dd[u + 4] = bx * bx + by * by + bz * bz;
            }
#pragma unroll
            for (int u = 0; u < 8; ++u) {
                if (__any(dd[u] < d2)) {
                    int jj = jbase + joff + j16 + u;
                    TOP3_INS(dd[u], jj, d0, d1, d2, i0, i1, i2);
                }
            }
        }

        // issue prefetch of next window A (local j16+16 .. j16+23).
        // Last iteration of wave 3 reads into the +8 pad; values are dead.
        int jn = joff + j16 + 16;
        ax0 = *(const float4*)&sx[jn];     ax1 = *(const float4*)&sx[jn + 4];
        ay0 = *(const float4*)&sy[jn];     ay1 = *(const float4*)&sy[jn + 4];
        az0 = *(const float4*)&sz[jn];     az1 = *(const float4*)&sz[jn + 4];

        // compute + insert window B (j16+8 .. j16+15)
        {
            float dd[8];
#pragma unroll
            for (int u = 0; u < 4; ++u) {
                float ax = px - bx0[u], ay = py - by0[u], az = pz - bz0[u];
                dd[u] = ax * ax + ay * ay + az * az;
                float bx = px - bx1[u], by = py - by1[u], bz = pz - bz1[u];
                dd[u + 4] = bx * bx + by * by + bz * bz;
            }
#pragma unroll
            for (int u = 0; u < 8; ++u) {
                if (__any(dd[u] < d2)) {
                    int jj = jbase + joff + j16 + 8 + u;
                    TOP3_INS(dd[u], jj, d0, d1, d2, i0, i1, i2);
                }
            }
        }
    }

    if (wave) {
        pd[(wave - 1) * 192 + lane * 3 + 0] = d0;
        pd[(wave - 1) * 192 + lane * 3 + 1] = d1;
        pd[(wave - 1) * 192 + lane * 3 + 2] = d2;
        pi[(wave - 1) * 192 + lane * 3 + 0] = i0;
        pi[(wave - 1) * 192 + lane * 3 + 1] = i1;
        pi[(wave - 1) * 192 + lane * 3 + 2] = i2;
    }
    __syncthreads();
    if (wave == 0) {
        // merge chunk 1..3 partials in chunk order -> jax top_k order.
#pragma unroll
        for (int c = 0; c < 3; ++c) {
#pragma unroll
            for (int s = 0; s < 3; ++s) {
                float d = pd[c * 192 + lane * 3 + s];
                int jj = pi[c * 192 + lane * 3 + s];
                TOP3_INS(d, jj, d0, d1, d2, i0, i1, i2);
            }
        }
        float w0 = 1.0f / fmaxf(d0, 1e-16f);
        float w1 = 1.0f / fmaxf(d1, 1e-16f);
        float w2 = 1.0f / fmaxf(d2, 1e-16f);
        float inv = 1.0f / (w0 + w1 + w2);
        idxw[m * 3 + 0] = i0;  wgt[m * 3 + 0] = w0 * inv;
        idxw[m * 3 + 1] = i1;  wgt[m * 3 + 1] = w1 * inv;
        idxw[m * 3 + 2] = i2;  wgt[m * 3 + 2] = w2 * inv;
    }
}

// ---- kernel 3: fused (r9 structure restored: full-staged wB, 72 KB, 2 blk/CU;
// r10's half-staging regressed ~9us). Round-11 change: A of gemm1 read from
// x_skip f32 with inline cast (ld_cvt8) instead of the xsb intermediate.
#define LDS_STRIDE 264
#define WB_STRIDE 72
__global__ __launch_bounds__(256) void fused_kernel(const float* __restrict__ x_skip,
                                                    const ushort* __restrict__ Bt1b,
                                                    const ushort* __restrict__ Gb,
                                                    const int* __restrict__ idxw,
                                                    const float* __restrict__ wgt,
                                                    const float* __restrict__ b1,
                                                    const ushort* __restrict__ Bt2,
                                                    const float* __restrict__ b2,
                                                    float* __restrict__ out) {
    __shared__ ushort h1t[4][16 * LDS_STRIDE];     // 33792 B
    __shared__ ushort wB[256 * WB_STRIDE];         // 36864 B
    __shared__ int   sIdx[4][48];
    __shared__ float sWgt[4][48];                  // total ~72 KB -> 2 blk/CU
    int tid = threadIdx.x;
    int wave = tid >> 6, lane = tid & 63;
    int m0 = blockIdx.x * 64 + wave * 16;
    int lrow = lane & 15;
    int ko = (lane >> 4) * 8;
    int rbase = (lane >> 4) * 4;

    if (lane < 48) {
        sIdx[wave][lane] = idxw[m0 * 3 + lane];
        sWgt[wave][lane] = wgt[m0 * 3 + lane];
    }

    const ushort4* Gv = (const ushort4*)Gb;
    const int*   si = sIdx[wave];
    const float* sw = sWgt[wave];
    ushort4 g[4][3];
#define GATHER(slot, i) {                                         \
        int a0 = si[(i) * 3 + 0];                                 \
        int a1 = si[(i) * 3 + 1];                                 \
        int a2 = si[(i) * 3 + 2];                                 \
        g[slot][0] = Gv[(size_t)a0 * 64 + lane];                  \
        g[slot][1] = Gv[(size_t)a1 * 64 + lane];                  \
        g[slot][2] = Gv[(size_t)a2 * 64 + lane]; }

    GATHER(0, 0) GATHER(1, 1) GATHER(2, 2) GATHER(3, 3)

    for (int cch = tid; cch < 2048; cch += 256) {
        int n = cch >> 3, koff = (cch & 7) * 8;
        *(short8*)&wB[n * WB_STRIDE + koff] = *(const short8*)(Bt1b + n * 64 + koff);
    }
    __syncthreads();

    floatx4 acc[16];
#pragma unroll
    for (int i = 0; i < 16; ++i) acc[i] = (floatx4){0.f, 0.f, 0.f, 0.f};
    {
        const float* arow = x_skip + (size_t)(m0 + lrow) * 64 + ko;
#pragma unroll
        for (int k0 = 0; k0 < 64; k0 += 32) {
            short8 af = ld_cvt8(arow + k0);
#pragma unroll
            for (int nt = 0; nt < 16; ++nt) {
                short8 bf = *(const short8*)&wB[(nt * 16 + lrow) * WB_STRIDE + k0 + ko];
                acc[nt] = __builtin_amdgcn_mfma_f32_16x16x32_bf16(af, bf, acc[nt], 0, 0, 0);
            }
        }
    }

    ushort* ht = h1t[wave];
#pragma unroll
    for (int nt = 0; nt < 16; ++nt) {
        int n = nt * 16 + lrow;
#pragma unroll
        for (int r = 0; r < 4; ++r)
            ht[(rbase + r) * LDS_STRIDE + n] = f2bf(acc[nt][r]);
    }

    {
        float4 bv = ((const float4*)b1)[lane];
#define COMBINE(i) {                                              \
        int s = (i) & 3;                                          \
        float w0 = sw[(i) * 3 + 0], w1 = sw[(i) * 3 + 1], w2 = sw[(i) * 3 + 2]; \
        ushort4 sv = *(const ushort4*)(ht + (i) * LDS_STRIDE + 4 * lane); \
        float4 h;                                                 \
        h.x = fmaxf(bf2f(sv.x) + w0 * bf2f(g[s][0].x) + w1 * bf2f(g[s][1].x) + w2 * bf2f(g[s][2].x) + bv.x, 0.f); \
        h.y = fmaxf(bf2f(sv.y) + w0 * bf2f(g[s][0].y) + w1 * bf2f(g[s][1].y) + w2 * bf2f(g[s][2].y) + bv.y, 0.f); \
        h.z = fmaxf(bf2f(sv.z) + w0 * bf2f(g[s][0].z) + w1 * bf2f(g[s][1].z) + w2 * bf2f(g[s][2].z) + bv.z, 0.f); \
        h.w = fmaxf(bf2f(sv.w) + w0 * bf2f(g[s][0].w) + w1 * bf2f(g[s][1].w) + w2 * bf2f(g[s][2].w) + bv.w, 0.f); \
        ushort4 hp;                                               \
        hp.x = f2bf(h.x); hp.y = f2bf(h.y); hp.z = f2bf(h.z); hp.w = f2bf(h.w); \
        *(ushort4*)(ht + (i) * LDS_STRIDE + 4 * lane) = hp; }

#pragma unroll
        for (int i = 0; i < 12; ++i) { COMBINE(i); GATHER(i & 3, i + 4); }
#pragma unroll
        for (int i = 12; i < 16; ++i) { COMBINE(i); }
#undef GATHER
#undef COMBINE
    }

#pragma unroll
    for (int i = 0; i < 16; ++i) acc[i] = (floatx4){0.f, 0.f, 0.f, 0.f};
    for (int s = 0; s < 4; ++s) {
        __syncthreads();
        for (int cch = tid; cch < 2048; cch += 256) {
            int n = cch >> 3, koff = (cch & 7) * 8;
            *(short8*)&wB[n * WB_STRIDE + koff] = *(const short8*)(Bt2 + n * 256 + s * 64 + koff);
        }
        __syncthreads();
        const ushort* ar = ht + lrow * LDS_STRIDE + s * 64 + ko;
#pragma unroll
        for (int k0 = 0; k0 < 64; k0 += 32) {
            short8 af = *(const short8*)(ar + k0);
#pragma unroll
            for (int nt = 0; nt < 16; ++nt) {
                short8 bf = *(const short8*)&wB[(nt * 16 + lrow) * WB_STRIDE + k0 + ko];
                acc[nt] = __builtin_amdgcn_mfma_f32_16x16x32_bf16(af, bf, acc[nt], 0, 0, 0);
            }
        }
    }
#pragma unroll
    for (int nt = 0; nt < 16; ++nt) {
        int n = nt * 16 + lrow;
        float bv2 = b2[n];
#pragma unroll
        for (int r = 0; r < 4; ++r) {
            float v = fmaxf(acc[nt][r] + bv2, 0.f);
            out[(size_t)(m0 + rbase + r) * OUTD + n] = v;
        }
    }
}

extern "C" void kernel_launch(void* const* d_in, const int* in_sizes, int n_in,
                              void* d_out, int out_size, void* d_ws, size_t ws_size,
                              hipStream_t stream) {
    const float* x        = (const float*)d_in[0];
    const float* pos      = (const float*)d_in[1];
    const float* x_skip   = (const float*)d_in[3];
    const float* pos_skip = (const float*)d_in[4];
    const float* W1       = (const float*)d_in[6];
    const float* b1       = (const float*)d_in[7];
    const float* W2       = (const float*)d_in[8];
    const float* b2       = (const float*)d_in[9];

    char* ws = (char*)d_ws;
    size_t off = 0;
    int*    idxw = (int*)(ws + off);    off += (size_t)MTOT * 3 * 4;      //  768 KB
    float*  wgt  = (float*)(ws + off);  off += (size_t)MTOT * 3 * 4;      //  768 KB
    ushort* Gb   = (ushort*)(ws + off); off += (size_t)NCTOT * 256 * 2;   //    8 MB
    ushort* Bt1a = (ushort*)(ws + off); off += (size_t)256 * 256 * 2;     //  128 KB
    ushort* Bt1b = (ushort*)(ws + off); off += (size_t)256 * 64 * 2;      //   32 KB
    ushort* Bt2  = (ushort*)(ws + off); off += (size_t)256 * 256 * 2;     //  128 KB
    float4* pos4 = (float4*)(ws + off); off += (size_t)(NCTOT + 8) * 16;  //  256 KB
    float* out = (float*)d_out;

    prep_all<<<PREP_BLOCKS, 256, 0, stream>>>(
        pos, pos_skip, W1, W2, pos4, Bt1a, Bt1b, Bt2, out);
    knn_gemm<<<KNN_BASE + MTOT / 64, 256, 0, stream>>>(
        pos4, pos_skip, idxw, wgt, x, Bt1a, Gb);
    fused_kernel<<<MTOT / 64, 256, 0, stream>>>(x_skip, Bt1b, Gb, idxw, wgt, b1, Bt2, b2, out);
}

// Round 13
// 194.648 us; speedup vs baseline: 1.0713x; 1.0070x over previous
//
#include <hip/hip_runtime.h>
#include <hip/hip_bf16.h>

#define BATCH 8
#define NC 2048
#define NF 8192
#define CDIM 256
#define CSKIP 64
#define OUTD 256
#define MTOT (BATCH*NF)   // 65536
#define NCTOT (BATCH*NC)  // 16384
#define KCH4 512          // per-wave coarse chunk (4 chunks x 2 point-groups)

typedef __attribute__((ext_vector_type(8))) short short8;
typedef __attribute__((ext_vector_type(4))) float floatx4;

static __device__ __forceinline__ ushort f2bf(float f) {
    union { float f; unsigned u; } v; v.f = f;
    unsigned r = v.u + 0x7fffu + ((v.u >> 16) & 1u);   // RNE
    return (ushort)(r >> 16);
}
static __device__ __forceinline__ float bf2f(ushort u) {
    union { unsigned u; float f; } v; v.u = ((unsigned)u) << 16;
    return v.f;
}
// load 8 f32 and convert to a bf16 short8 fragment (bit-identical to the
// old prep-cast + bf16 reload path; the cast is just fused into the consumer)
static __device__ __forceinline__ short8 ld_cvt8(const float* __restrict__ p) {
    float4 a = *(const float4*)p;
    float4 b = *(const float4*)(p + 4);
    short8 r;
    r[0] = (short)f2bf(a.x); r[1] = (short)f2bf(a.y);
    r[2] = (short)f2bf(a.z); r[3] = (short)f2bf(a.w);
    r[4] = (short)f2bf(b.x); r[5] = (short)f2bf(b.y);
    r[6] = (short)f2bf(b.z); r[7] = (short)f2bf(b.w);
    return r;
}

#if defined(__has_builtin) && __has_builtin(__builtin_amdgcn_fmed3f)
#define MED3F(a, b, c) __builtin_amdgcn_fmed3f((a), (b), (c))
#else
static __device__ __forceinline__ float MED3F(float a, float b, float c) {
    return fmaxf(fminf(a, b), fminf(fmaxf(a, b), c));
}
#endif

// branchless strict-< top-3 insert, parametrized state (exact jax top_k tie order
// when fed ascending j)
#define TOP3_INS(d, jj, D0, D1, D2, I0, I1, I2)     \
    {                                               \
        bool c2 = (d) < D2, c1 = (d) < D1, c0 = (d) < D0; \
        I2 = c1 ? I1 : (c2 ? (jj) : I2);            \
        I1 = c0 ? I0 : (c1 ? (jj) : I1);            \
        I0 = c0 ? (jj) : I0;                        \
        D2 = MED3F(D1, D2, (d));                    \
        D1 = MED3F(D0, D1, (d));                    \
        D0 = fminf(D0, (d));                        \
    }

// ---- kernel 1: prep_all = weight transpose (blocks 0..35) + pos4/out-tail.
#define SEG5 16384     // pos -> pos4
#define SEG6 (MTOT*3)  // pos_skip -> out tail
#define SEG7 MTOT      // batch ids -> out tail
#define PREP_THREADS (SEG5+SEG6+SEG7)
#define PW_BLOCKS 36
#define PREP_BLOCKS (PW_BLOCKS + (PREP_THREADS + 255) / 256)

__global__ __launch_bounds__(256) void prep_all(const float* __restrict__ pos,
                                                const float* __restrict__ pos_skip,
                                                const float* __restrict__ W1,
                                                const float* __restrict__ W2,
                                                float4* __restrict__ pos4,
                                                ushort* __restrict__ Bt1a,
                                                ushort* __restrict__ Bt1b,
                                                ushort* __restrict__ Bt2,
                                                float* __restrict__ out) {
    __shared__ ushort tile[64 * 65];
    if (blockIdx.x < PW_BLOCKS) {
        // ---- weight transpose (64x64 LDS tiles, pad 65)
        int bid = blockIdx.x;
        const float* src; ushort* dst; int k0, n0, KD;
        if (bid < 16)      { src = W1;             dst = Bt1a; k0 = (bid >> 2) * 64; n0 = (bid & 3) * 64; KD = 256; }
        else if (bid < 20) { src = W1 + 256 * 256; dst = Bt1b; k0 = 0;               n0 = (bid - 16) * 64; KD = 64; }
        else               { int b2 = bid - 20; src = W2; dst = Bt2; k0 = (b2 >> 2) * 64; n0 = (b2 & 3) * 64; KD = 256; }
        int tx = threadIdx.x & 63, ty = threadIdx.x >> 6;
#pragma unroll
        for (int r = 0; r < 64; r += 4) {
            int k = r + ty;
            tile[k * 65 + tx] = f2bf(src[(size_t)(k0 + k) * 256 + n0 + tx]);
        }
        __syncthreads();
#pragma unroll
        for (int r = 0; r < 64; r += 4) {
            int n = r + ty;
            dst[(size_t)(n0 + n) * KD + k0 + tx] = tile[tx * 65 + n];
        }
        return;
    }
    int t = (blockIdx.x - PW_BLOCKS) * 256 + threadIdx.x;
    if (t < SEG5) {
        float4 q;
        q.x = pos[t * 3 + 0]; q.y = pos[t * 3 + 1]; q.z = pos[t * 3 + 2]; q.w = 0.f;
        pos4[t] = q;
        return;
    }
    t -= SEG5;
    if (t < SEG6) {
        out[(size_t)MTOT * OUTD + t] = pos_skip[t];
        return;
    }
    t -= SEG6;
    if (t < SEG7) {
        out[(size_t)MTOT * OUTD + (size_t)MTOT * 3 + t] = (float)(t >> 13);
    }
}

// ---- kernel 2: knn_gemm — heterogeneous dispatch, 512-thr blocks.
// Round-12 failed: 4-group layout spanned 256 points on a 128-point grid
// stride -> blocks at kb%64==63 crossed the 8192 cloud boundary; per-thread
// jbase + block-shared staging mixed two clouds' coarse points. Round-13
// fix: 8 waves = 2 point-groups x 4 chunks of 512 (proven C=512 geometry),
// block owns exactly 128 points (128 | 8192 -> cloud-uniform, staging safe).
// Keeps r12's sound parts: staging amortized over 2x points, 640-block grid
// -> avg 2.5 blk/CU = 5 waves/SIMD; 512-thr gemm path (128 rows/block).
// launch_bounds (512,4) not (512,6): gemm's 64-VGPR acc must not spill.
// Inner loop / tie order / 3-partial chunk-order merge verbatim r8/r11.
#define GW_STRIDE 72
#define GEMM_BLOCKS 128
__global__ __launch_bounds__(512, 4) void knn_gemm(const float4* __restrict__ pos4,
                                                   const float* __restrict__ pos_skip,
                                                   int* __restrict__ idxw,
                                                   float* __restrict__ wgt,
                                                   const float* __restrict__ X,
                                                   const ushort* __restrict__ Bt,
                                                   ushort* __restrict__ Gb) {
    __shared__ __align__(16) char smem[36864];
    int tid = threadIdx.x;
    int wave = tid >> 6;
    int lane = tid & 63;

    if (blockIdx.x < GEMM_BLOCKS) {
        // ====== gemm_G: Gb = bf16( bf16(x) @ Bt1a^T ), A cast inline ======
        ushort* wB = (ushort*)smem;                    // 256*72 ushort = 36 KB
        int m0 = blockIdx.x * 128 + wave * 16;
        int lrow = lane & 15;
        int ko = (lane >> 4) * 8;

        floatx4 acc[16];
#pragma unroll
        for (int i = 0; i < 16; ++i) acc[i] = (floatx4){0.f, 0.f, 0.f, 0.f};

        for (int s = 0; s < 4; ++s) {
            if (s) __syncthreads();
            for (int cch = tid; cch < 2048; cch += 512) {
                int n = cch >> 3, koff = (cch & 7) * 8;
                *(short8*)&wB[n * GW_STRIDE + koff] = *(const short8*)(Bt + n * 256 + s * 64 + koff);
            }
            __syncthreads();
            const float* ar = X + (size_t)(m0 + lrow) * 256 + s * 64 + ko;
#pragma unroll
            for (int k0 = 0; k0 < 64; k0 += 32) {
                short8 af = ld_cvt8(ar + k0);
#pragma unroll
                for (int nt = 0; nt < 16; ++nt) {
                    short8 bf = *(const short8*)&wB[(nt * 16 + lrow) * GW_STRIDE + k0 + ko];
                    acc[nt] = __builtin_amdgcn_mfma_f32_16x16x32_bf16(af, bf, acc[nt], 0, 0, 0);
                }
            }
        }
        int rbase = (lane >> 4) * 4;
#pragma unroll
        for (int nt = 0; nt < 16; ++nt) {
            int n = nt * 16 + lrow;
#pragma unroll
            for (int r = 0; r < 4; ++r)
                Gb[(size_t)(m0 + rbase + r) * 256 + n] = f2bf(acc[nt][r]);
        }
        return;
    }

    // ========== knn: 2 point-groups x 4 chunks of 512 per block ==========
    float* sx = (float*)smem;                      // NC+8 floats
    float* sy = sx + (NC + 8);
    float* sz = sy + (NC + 8);
    float* pd = sz + (NC + 8);                     // 2 grp * 3 chunk-partials * 192
    int*   pi = (int*)(pd + 6 * 192);              // same (33.9 KB total)

    int kb = blockIdx.x - GEMM_BLOCKS;
    int grp = wave >> 2;            // point-group 0..1 (64 pts each)
    int chk = wave & 3;             // coarse chunk 0..3
    int m = kb * 128 + grp * 64 + lane;
    int b = m >> 13;                // block spans 128 pts, 128 | 8192 -> uniform
    int jbase = b * NC;

    for (int i = tid; i < NC; i += 512) {
        float4 q = pos4[jbase + i];
        sx[i] = q.x; sy[i] = q.y; sz[i] = q.z;
    }
    float px = pos_skip[m * 3 + 0];
    float py = pos_skip[m * 3 + 1];
    float pz = pos_skip[m * 3 + 2];
    __syncthreads();

    int joff = chk * KCH4;

    float d0 = 1e30f, d1 = 1e30f, d2 = 1e30f;
    int i0 = jbase, i1 = jbase, i2 = jbase;

    // preload window 0 (local j 0..7) into A registers
    float4 ax0 = *(const float4*)&sx[joff],     ax1 = *(const float4*)&sx[joff + 4];
    float4 ay0 = *(const float4*)&sy[joff],     ay1 = *(const float4*)&sy[joff + 4];
    float4 az0 = *(const float4*)&sz[joff],     az1 = *(const float4*)&sz[joff + 4];

    for (int j16 = 0; j16 < KCH4; j16 += 16) {
        // issue prefetch of window B (local j16+8 .. j16+15)
        int jb2 = joff + j16 + 8;
        float4 bx0 = *(const float4*)&sx[jb2],     bx1 = *(const float4*)&sx[jb2 + 4];
        float4 by0 = *(const float4*)&sy[jb2],     by1 = *(const float4*)&sy[jb2 + 4];
        float4 bz0 = *(const float4*)&sz[jb2],     bz1 = *(const float4*)&sz[jb2 + 4];

        // compute + insert window A (j16 .. j16+7) — hides B's LDS latency
        {
            float dd[8];
#pragma unroll
            for (int u = 0; u < 4; ++u) {
                float ax = px - ax0[u], ay = py - ay0[u], az = pz - az0[u];
                dd[u] = ax * ax + ay * ay + az * az;
                float bx = px - ax1[u], by = py - ay1[u], bz = pz - az1[u];
                dd[u + 4] = bx * bx + by * by + bz * bz;
            }
#pragma unroll
            for (int u = 0; u < 8; ++u) {
                if (__any(dd[u] < d2)) {
                    int jj = jbase + joff + j16 + u;
                    TOP3_INS(dd[u], jj, d0, d1, d2, i0, i1, i2);
                }
            }
        }

        // issue prefetch of next window A (local j16+16 .. j16+23).
        // Last iteration: chunks 0-2 read the next chunk's data (discarded),
        // chunk 3 reads the +8 pad; loop exits before consumption.
        int jn = joff + j16 + 16;
        ax0 = *(const float4*)&sx[jn];     ax1 = *(const float4*)&sx[jn + 4];
        ay0 = *(const float4*)&sy[jn];     ay1 = *(const float4*)&sy[jn + 4];
        az0 = *(const float4*)&sz[jn];     az1 = *(const float4*)&sz[jn + 4];

        // compute + insert window B (j16+8 .. j16+15)
        {
            float dd[8];
#pragma unroll
            for (int u = 0; u < 4; ++u) {
                float ax = px - bx0[u], ay = py - by0[u], az = pz - bz0[u];
                dd[u] = ax * ax + ay * ay + az * az;
                float bx = px - bx1[u], by = py - by1[u], bz = pz - bz1[u];
                dd[u + 4] = bx * bx + by * by + bz * bz;
            }
#pragma unroll
            for (int u = 0; u < 8; ++u) {
                if (__any(dd[u] < d2)) {
                    int jj = jbase + joff + j16 + 8 + u;
                    TOP3_INS(dd[u], jj, d0, d1, d2, i0, i1, i2);
                }
            }
        }
    }

    if (chk) {
        int pbase = (grp * 3 + (chk - 1)) * 192 + lane * 3;
        pd[pbase + 0] = d0; pd[pbase + 1] = d1; pd[pbase + 2] = d2;
        pi[pbase + 0] = i0; pi[pbase + 1] = i1; pi[pbase + 2] = i2;
    }
    __syncthreads();
    if (chk == 0) {
        // merge chunk 1..3 partials in chunk order (all chunk-c j < chunk-c+1
        // j; within-partial d0<=d1<=d2, ascending-j ties) -> jax top_k order.
#pragma unroll
        for (int c = 0; c < 3; ++c) {
            int pbase = (grp * 3 + c) * 192 + lane * 3;
#pragma unroll
            for (int s = 0; s < 3; ++s) {
                float d = pd[pbase + s];
                int jj = pi[pbase + s];
                TOP3_INS(d, jj, d0, d1, d2, i0, i1, i2);
            }
        }
        float w0 = 1.0f / fmaxf(d0, 1e-16f);
        float w1 = 1.0f / fmaxf(d1, 1e-16f);
        float w2 = 1.0f / fmaxf(d2, 1e-16f);
        float inv = 1.0f / (w0 + w1 + w2);
        idxw[m * 3 + 0] = i0;  wgt[m * 3 + 0] = w0 * inv;
        idxw[m * 3 + 1] = i1;  wgt[m * 3 + 1] = w1 * inv;
        idxw[m * 3 + 2] = i2;  wgt[m * 3 + 2] = w2 * inv;
    }
}

// ---- kernel 3: fused (r11 structure: full-staged wB, 72 KB, 2 blk/CU;
// gemm1 A read from x_skip f32 with inline cast).
#define LDS_STRIDE 264
#define WB_STRIDE 72
__global__ __launch_bounds__(256) void fused_kernel(const float* __restrict__ x_skip,
                                                    const ushort* __restrict__ Bt1b,
                                                    const ushort* __restrict__ Gb,
                                                    const int* __restrict__ idxw,
                                                    const float* __restrict__ wgt,
                                                    const float* __restrict__ b1,
                                                    const ushort* __restrict__ Bt2,
                                                    const float* __restrict__ b2,
                                                    float* __restrict__ out) {
    __shared__ ushort h1t[4][16 * LDS_STRIDE];     // 33792 B
    __shared__ ushort wB[256 * WB_STRIDE];         // 36864 B
    __shared__ int   sIdx[4][48];
    __shared__ float sWgt[4][48];                  // total ~72 KB -> 2 blk/CU
    int tid = threadIdx.x;
    int wave = tid >> 6, lane = tid & 63;
    int m0 = blockIdx.x * 64 + wave * 16;
    int lrow = lane & 15;
    int ko = (lane >> 4) * 8;
    int rbase = (lane >> 4) * 4;

    if (lane < 48) {
        sIdx[wave][lane] = idxw[m0 * 3 + lane];
        sWgt[wave][lane] = wgt[m0 * 3 + lane];
    }

    const ushort4* Gv = (const ushort4*)Gb;
    const int*   si = sIdx[wave];
    const float* sw = sWgt[wave];
    ushort4 g[4][3];
#define GATHER(slot, i) {                                         \
        int a0 = si[(i) * 3 + 0];                                 \
        int a1 = si[(i) * 3 + 1];                                 \
        int a2 = si[(i) * 3 + 2];                                 \
        g[slot][0] = Gv[(size_t)a0 * 64 + lane];                  \
        g[slot][1] = Gv[(size_t)a1 * 64 + lane];                  \
        g[slot][2] = Gv[(size_t)a2 * 64 + lane]; }

    GATHER(0, 0) GATHER(1, 1) GATHER(2, 2) GATHER(3, 3)

    for (int cch = tid; cch < 2048; cch += 256) {
        int n = cch >> 3, koff = (cch & 7) * 8;
        *(short8*)&wB[n * WB_STRIDE + koff] = *(const short8*)(Bt1b + n * 64 + koff);
    }
    __syncthreads();

    floatx4 acc[16];
#pragma unroll
    for (int i = 0; i < 16; ++i) acc[i] = (floatx4){0.f, 0.f, 0.f, 0.f};
    {
        const float* arow = x_skip + (size_t)(m0 + lrow) * 64 + ko;
#pragma unroll
        for (int k0 = 0; k0 < 64; k0 += 32) {
            short8 af = ld_cvt8(arow + k0);
#pragma unroll
            for (int nt = 0; nt < 16; ++nt) {
                short8 bf = *(const short8*)&wB[(nt * 16 + lrow) * WB_STRIDE + k0 + ko];
                acc[nt] = __builtin_amdgcn_mfma_f32_16x16x32_bf16(af, bf, acc[nt], 0, 0, 0);
            }
        }
    }

    ushort* ht = h1t[wave];
#pragma unroll
    for (int nt = 0; nt < 16; ++nt) {
        int n = nt * 16 + lrow;
#pragma unroll
        for (int r = 0; r < 4; ++r)
            ht[(rbase + r) * LDS_STRIDE + n] = f2bf(acc[nt][r]);
    }

    {
        float4 bv = ((const float4*)b1)[lane];
#define COMBINE(i) {                                              \
        int s = (i) & 3;                                          \
        float w0 = sw[(i) * 3 + 0], w1 = sw[(i) * 3 + 1], w2 = sw[(i) * 3 + 2]; \
        ushort4 sv = *(const ushort4*)(ht + (i) * LDS_STRIDE + 4 * lane); \
        float4 h;                                                 \
        h.x = fmaxf(bf2f(sv.x) + w0 * bf2f(g[s][0].x) + w1 * bf2f(g[s][1].x) + w2 * bf2f(g[s][2].x) + bv.x, 0.f); \
        h.y = fmaxf(bf2f(sv.y) + w0 * bf2f(g[s][0].y) + w1 * bf2f(g[s][1].y) + w2 * bf2f(g[s][2].y) + bv.y, 0.f); \
        h.z = fmaxf(bf2f(sv.z) + w0 * bf2f(g[s][0].z) + w1 * bf2f(g[s][1].z) + w2 * bf2f(g[s][2].z) + bv.z, 0.f); \
        h.w = fmaxf(bf2f(sv.w) + w0 * bf2f(g[s][0].w) + w1 * bf2f(g[s][1].w) + w2 * bf2f(g[s][2].w) + bv.w, 0.f); \
        ushort4 hp;                                               \
        hp.x = f2bf(h.x); hp.y = f2bf(h.y); hp.z = f2bf(h.z); hp.w = f2bf(h.w); \
        *(ushort4*)(ht + (i) * LDS_STRIDE + 4 * lane) = hp; }

#pragma unroll
        for (int i = 0; i < 12; ++i) { COMBINE(i); GATHER(i & 3, i + 4); }
#pragma unroll
        for (int i = 12; i < 16; ++i) { COMBINE(i); }
#undef GATHER
#undef COMBINE
    }

#pragma unroll
    for (int i = 0; i < 16; ++i) acc[i] = (floatx4){0.f, 0.f, 0.f, 0.f};
    for (int s = 0; s < 4; ++s) {
        __syncthreads();
        for (int cch = tid; cch < 2048; cch += 256) {
            int n = cch >> 3, koff = (cch & 7) * 8;
            *(short8*)&wB[n * WB_STRIDE + koff] = *(const short8*)(Bt2 + n * 256 + s * 64 + koff);
        }
        __syncthreads();
        const ushort* ar = ht + lrow * LDS_STRIDE + s * 64 + ko;
#pragma unroll
        for (int k0 = 0; k0 < 64; k0 += 32) {
            short8 af = *(const short8*)(ar + k0);
#pragma unroll
            for (int nt = 0; nt < 16; ++nt) {
                short8 bf = *(const short8*)&wB[(nt * 16 + lrow) * WB_STRIDE + k0 + ko];
                acc[nt] = __builtin_amdgcn_mfma_f32_16x16x32_bf16(af, bf, acc[nt], 0, 0, 0);
            }
        }
    }
#pragma unroll
    for (int nt = 0; nt < 16; ++nt) {
        int n = nt * 16 + lrow;
        float bv2 = b2[n];
#pragma unroll
        for (int r = 0; r < 4; ++r) {
            float v = fmaxf(acc[nt][r] + bv2, 0.f);
            out[(size_t)(m0 + rbase + r) * OUTD + n] = v;
        }
    }
}

extern "C" void kernel_launch(void* const* d_in, const int* in_sizes, int n_in,
                              void* d_out, int out_size, void* d_ws, size_t ws_size,
                              hipStream_t stream) {
    const float* x        = (const float*)d_in[0];
    const float* pos      = (const float*)d_in[1];
    const float* x_skip   = (const float*)d_in[3];
    const float* pos_skip = (const float*)d_in[4];
    const float* W1       = (const float*)d_in[6];
    const float* b1       = (const float*)d_in[7];
    const float* W2       = (const float*)d_in[8];
    const float* b2       = (const float*)d_in[9];

    char* ws = (char*)d_ws;
    size_t off = 0;
    int*    idxw = (int*)(ws + off);    off += (size_t)MTOT * 3 * 4;      //  768 KB
    float*  wgt  = (float*)(ws + off);  off += (size_t)MTOT * 3 * 4;      //  768 KB
    ushort* Gb   = (ushort*)(ws + off); off += (size_t)NCTOT * 256 * 2;   //    8 MB
    ushort* Bt1a = (ushort*)(ws + off); off += (size_t)256 * 256 * 2;     //  128 KB
    ushort* Bt1b = (ushort*)(ws + off); off += (size_t)256 * 64 * 2;      //   32 KB
    ushort* Bt2  = (ushort*)(ws + off); off += (size_t)256 * 256 * 2;     //  128 KB
    float4* pos4 = (float4*)(ws + off); off += (size_t)(NCTOT + 8) * 16;  //  256 KB
    float* out = (float*)d_out;

    prep_all<<<PREP_BLOCKS, 256, 0, stream>>>(
        pos, pos_skip, W1, W2, pos4, Bt1a, Bt1b, Bt2, out);
    knn_gemm<<<GEMM_BLOCKS + MTOT / 128, 512, 0, stream>>>(
        pos4, pos_skip, idxw, wgt, x, Bt1a, Gb);
    fused_kernel<<<MTOT / 64, 256, 0, stream>>>(x_skip, Bt1b, Gb, idxw, wgt, b1, Bt2, b2, out);
}

// Round 14
// 193.861 us; speedup vs baseline: 1.0756x; 1.0041x over previous
//
#include <hip/hip_runtime.h>
#include <hip/hip_bf16.h>

#define BATCH 8
#define NC 2048
#define NF 8192
#define CDIM 256
#define CSKIP 64
#define OUTD 256
#define MTOT (BATCH*NF)   // 65536
#define NCTOT (BATCH*NC)  // 16384
#define KCH4 512          // per-wave coarse chunk (4 chunks x 2 point-groups)

typedef __attribute__((ext_vector_type(8))) short short8;
typedef __attribute__((ext_vector_type(4))) float floatx4;

static __device__ __forceinline__ ushort f2bf(float f) {
    union { float f; unsigned u; } v; v.f = f;
    unsigned r = v.u + 0x7fffu + ((v.u >> 16) & 1u);   // RNE
    return (ushort)(r >> 16);
}
static __device__ __forceinline__ float bf2f(ushort u) {
    union { unsigned u; float f; } v; v.u = ((unsigned)u) << 16;
    return v.f;
}
// load 8 f32 and convert to a bf16 short8 fragment (bit-identical to the
// old prep-cast + bf16 reload path; the cast is just fused into the consumer)
static __device__ __forceinline__ short8 ld_cvt8(const float* __restrict__ p) {
    float4 a = *(const float4*)p;
    float4 b = *(const float4*)(p + 4);
    short8 r;
    r[0] = (short)f2bf(a.x); r[1] = (short)f2bf(a.y);
    r[2] = (short)f2bf(a.z); r[3] = (short)f2bf(a.w);
    r[4] = (short)f2bf(b.x); r[5] = (short)f2bf(b.y);
    r[6] = (short)f2bf(b.z); r[7] = (short)f2bf(b.w);
    return r;
}

#if defined(__has_builtin) && __has_builtin(__builtin_amdgcn_fmed3f)
#define MED3F(a, b, c) __builtin_amdgcn_fmed3f((a), (b), (c))
#else
static __device__ __forceinline__ float MED3F(float a, float b, float c) {
    return fmaxf(fminf(a, b), fminf(fmaxf(a, b), c));
}
#endif

// branchless strict-< top-3 insert, parametrized state (exact jax top_k tie order
// when fed ascending j)
#define TOP3_INS(d, jj, D0, D1, D2, I0, I1, I2)     \
    {                                               \
        bool c2 = (d) < D2, c1 = (d) < D1, c0 = (d) < D0; \
        I2 = c1 ? I1 : (c2 ? (jj) : I2);            \
        I1 = c0 ? I0 : (c1 ? (jj) : I1);            \
        I0 = c0 ? (jj) : I0;                        \
        D2 = MED3F(D1, D2, (d));                    \
        D1 = MED3F(D0, D1, (d));                    \
        D0 = fminf(D0, (d));                        \
    }

// ---- kernel 1: prep_w — weight transposes ONLY (36 blocks). Round-14: the
// pos->pos4 repack is deleted (knn stages from pos directly) and the out-tail
// writes moved into knn_gemm's grid shadow; prep shrinks 1124 -> 36 blocks.
__global__ __launch_bounds__(256) void prep_w(const float* __restrict__ W1,
                                              const float* __restrict__ W2,
                                              ushort* __restrict__ Bt1a,
                                              ushort* __restrict__ Bt1b,
                                              ushort* __restrict__ Bt2) {
    __shared__ ushort tile[64 * 65];
    int bid = blockIdx.x;
    const float* src; ushort* dst; int k0, n0, KD;
    if (bid < 16)      { src = W1;             dst = Bt1a; k0 = (bid >> 2) * 64; n0 = (bid & 3) * 64; KD = 256; }
    else if (bid < 20) { src = W1 + 256 * 256; dst = Bt1b; k0 = 0;               n0 = (bid - 16) * 64; KD = 64; }
    else               { int b2 = bid - 20; src = W2; dst = Bt2; k0 = (b2 >> 2) * 64; n0 = (b2 & 3) * 64; KD = 256; }
    int tx = threadIdx.x & 63, ty = threadIdx.x >> 6;
#pragma unroll
    for (int r = 0; r < 64; r += 4) {
        int k = r + ty;
        tile[k * 65 + tx] = f2bf(src[(size_t)(k0 + k) * 256 + n0 + tx]);
    }
    __syncthreads();
#pragma unroll
    for (int r = 0; r < 64; r += 4) {
        int n = r + ty;
        dst[(size_t)(n0 + n) * KD + k0 + tx] = tile[tx * 65 + n];
    }
}

// ---- kernel 2: knn_gemm — heterogeneous dispatch, 512-thr blocks.
// blocks [0,128): gemm (r13 verbatim); [128,640): knn (r13 loop, staging
// straight from pos: 3 scalar f32/pt, wave spans 768 contiguous B -> L1-hot);
// [640,768): out-tail float4 writers (pos_skip copy + batch ids) — appended
// last so they run in the CU shadow as knn blocks drain. Tail region of out
// is written by nobody else and read by nobody -> ordering-safe.
#define GW_STRIDE 72
#define GEMM_BLOCKS 128
#define KNN_BLOCKS 512
#define TAIL_BASE (GEMM_BLOCKS + KNN_BLOCKS)
#define TAIL_V4_A (MTOT * 3 / 4)   // 49152 float4 of pos_skip
#define TAIL_V4_B (MTOT / 4)       // 16384 float4 of batch ids
#define TAIL_BLOCKS ((TAIL_V4_A + TAIL_V4_B) / 512)   // 128
__global__ __launch_bounds__(512, 4) void knn_gemm(const float* __restrict__ pos,
                                                   const float* __restrict__ pos_skip,
                                                   int* __restrict__ idxw,
                                                   float* __restrict__ wgt,
                                                   const float* __restrict__ X,
                                                   const ushort* __restrict__ Bt,
                                                   ushort* __restrict__ Gb,
                                                   float* __restrict__ out) {
    __shared__ __align__(16) char smem[36864];
    int tid = threadIdx.x;
    int wave = tid >> 6;
    int lane = tid & 63;

    if (blockIdx.x >= TAIL_BASE) {
        // ================= out-tail writers (float4) =================
        int u = (blockIdx.x - TAIL_BASE) * 512 + tid;
        if (u < TAIL_V4_A) {
            ((float4*)(out + (size_t)MTOT * OUTD))[u] = ((const float4*)pos_skip)[u];
        } else {
            int v = u - TAIL_V4_A;
            float bid = (float)((v * 4) >> 13);
            float4 q; q.x = bid; q.y = bid; q.z = bid; q.w = bid;
            ((float4*)(out + (size_t)MTOT * OUTD + (size_t)MTOT * 3))[v] = q;
        }
        return;
    }

    if (blockIdx.x < GEMM_BLOCKS) {
        // ====== gemm_G: Gb = bf16( bf16(x) @ Bt1a^T ), A cast inline ======
        ushort* wB = (ushort*)smem;                    // 256*72 ushort = 36 KB
        int m0 = blockIdx.x * 128 + wave * 16;
        int lrow = lane & 15;
        int ko = (lane >> 4) * 8;

        floatx4 acc[16];
#pragma unroll
        for (int i = 0; i < 16; ++i) acc[i] = (floatx4){0.f, 0.f, 0.f, 0.f};

        for (int s = 0; s < 4; ++s) {
            if (s) __syncthreads();
            for (int cch = tid; cch < 2048; cch += 512) {
                int n = cch >> 3, koff = (cch & 7) * 8;
                *(short8*)&wB[n * GW_STRIDE + koff] = *(const short8*)(Bt + n * 256 + s * 64 + koff);
            }
            __syncthreads();
            const float* ar = X + (size_t)(m0 + lrow) * 256 + s * 64 + ko;
#pragma unroll
            for (int k0 = 0; k0 < 64; k0 += 32) {
                short8 af = ld_cvt8(ar + k0);
#pragma unroll
                for (int nt = 0; nt < 16; ++nt) {
                    short8 bf = *(const short8*)&wB[(nt * 16 + lrow) * GW_STRIDE + k0 + ko];
                    acc[nt] = __builtin_amdgcn_mfma_f32_16x16x32_bf16(af, bf, acc[nt], 0, 0, 0);
                }
            }
        }
        int rbase = (lane >> 4) * 4;
#pragma unroll
        for (int nt = 0; nt < 16; ++nt) {
            int n = nt * 16 + lrow;
#pragma unroll
            for (int r = 0; r < 4; ++r)
                Gb[(size_t)(m0 + rbase + r) * 256 + n] = f2bf(acc[nt][r]);
        }
        return;
    }

    // ========== knn: 2 point-groups x 4 chunks of 512 per block ==========
    float* sx = (float*)smem;                      // NC+8 floats
    float* sy = sx + (NC + 8);
    float* sz = sy + (NC + 8);
    float* pd = sz + (NC + 8);                     // 2 grp * 3 chunk-partials * 192
    int*   pi = (int*)(pd + 6 * 192);              // same (33.9 KB total)

    int kb = blockIdx.x - GEMM_BLOCKS;
    int grp = wave >> 2;            // point-group 0..1 (64 pts each)
    int chk = wave & 3;             // coarse chunk 0..3
    int m = kb * 128 + grp * 64 + lane;
    int b = m >> 13;                // block spans 128 pts, 128 | 8192 -> uniform
    int jbase = b * NC;

    for (int i = tid; i < NC; i += 512) {
        const float* pp = pos + (size_t)(jbase + i) * 3;
        sx[i] = pp[0]; sy[i] = pp[1]; sz[i] = pp[2];
    }
    float px = pos_skip[m * 3 + 0];
    float py = pos_skip[m * 3 + 1];
    float pz = pos_skip[m * 3 + 2];
    __syncthreads();

    int joff = chk * KCH4;

    float d0 = 1e30f, d1 = 1e30f, d2 = 1e30f;
    int i0 = jbase, i1 = jbase, i2 = jbase;

    // preload window 0 (local j 0..7) into A registers
    float4 ax0 = *(const float4*)&sx[joff],     ax1 = *(const float4*)&sx[joff + 4];
    float4 ay0 = *(const float4*)&sy[joff],     ay1 = *(const float4*)&sy[joff + 4];
    float4 az0 = *(const float4*)&sz[joff],     az1 = *(const float4*)&sz[joff + 4];

    for (int j16 = 0; j16 < KCH4; j16 += 16) {
        // issue prefetch of window B (local j16+8 .. j16+15)
        int jb2 = joff + j16 + 8;
        float4 bx0 = *(const float4*)&sx[jb2],     bx1 = *(const float4*)&sx[jb2 + 4];
        float4 by0 = *(const float4*)&sy[jb2],     by1 = *(const float4*)&sy[jb2 + 4];
        float4 bz0 = *(const float4*)&sz[jb2],     bz1 = *(const float4*)&sz[jb2 + 4];

        // compute + insert window A (j16 .. j16+7) — hides B's LDS latency
        {
            float dd[8];
#pragma unroll
            for (int u = 0; u < 4; ++u) {
                float ax = px - ax0[u], ay = py - ay0[u], az = pz - az0[u];
                dd[u] = ax * ax + ay * ay + az * az;
                float bx = px - ax1[u], by = py - ay1[u], bz = pz - az1[u];
                dd[u + 4] = bx * bx + by * by + bz * bz;
            }
#pragma unroll
            for (int u = 0; u < 8; ++u) {
                if (__any(dd[u] < d2)) {
                    int jj = jbase + joff + j16 + u;
                    TOP3_INS(dd[u], jj, d0, d1, d2, i0, i1, i2);
                }
            }
        }

        // issue prefetch of next window A (local j16+16 .. j16+23).
        // Last iteration: chunks 0-2 read the next chunk's data (discarded),
        // chunk 3 reads the +8 pad; loop exits before consumption.
        int jn = joff + j16 + 16;
        ax0 = *(const float4*)&sx[jn];     ax1 = *(const float4*)&sx[jn + 4];
        ay0 = *(const float4*)&sy[jn];     ay1 = *(const float4*)&sy[jn + 4];
        az0 = *(const float4*)&sz[jn];     az1 = *(const float4*)&sz[jn + 4];

        // compute + insert window B (j16+8 .. j16+15)
        {
            float dd[8];
#pragma unroll
            for (int u = 0; u < 4; ++u) {
                float ax = px - bx0[u], ay = py - by0[u], az = pz - bz0[u];
                dd[u] = ax * ax + ay * ay + az * az;
                float bx = px - bx1[u], by = py - by1[u], bz = pz - bz1[u];
                dd[u + 4] = bx * bx + by * by + bz * bz;
            }
#pragma unroll
            for (int u = 0; u < 8; ++u) {
                if (__any(dd[u] < d2)) {
                    int jj = jbase + joff + j16 + 8 + u;
                    TOP3_INS(dd[u], jj, d0, d1, d2, i0, i1, i2);
                }
            }
        }
    }

    if (chk) {
        int pbase = (grp * 3 + (chk - 1)) * 192 + lane * 3;
        pd[pbase + 0] = d0; pd[pbase + 1] = d1; pd[pbase + 2] = d2;
        pi[pbase + 0] = i0; pi[pbase + 1] = i1; pi[pbase + 2] = i2;
    }
    __syncthreads();
    if (chk == 0) {
        // merge chunk 1..3 partials in chunk order (all chunk-c j < chunk-c+1
        // j; within-partial d0<=d1<=d2, ascending-j ties) -> jax top_k order.
#pragma unroll
        for (int c = 0; c < 3; ++c) {
            int pbase = (grp * 3 + c) * 192 + lane * 3;
#pragma unroll
            for (int s = 0; s < 3; ++s) {
                float d = pd[pbase + s];
                int jj = pi[pbase + s];
                TOP3_INS(d, jj, d0, d1, d2, i0, i1, i2);
            }
        }
        float w0 = 1.0f / fmaxf(d0, 1e-16f);
        float w1 = 1.0f / fmaxf(d1, 1e-16f);
        float w2 = 1.0f / fmaxf(d2, 1e-16f);
        float inv = 1.0f / (w0 + w1 + w2);
        idxw[m * 3 + 0] = i0;  wgt[m * 3 + 0] = w0 * inv;
        idxw[m * 3 + 1] = i1;  wgt[m * 3 + 1] = w1 * inv;
        idxw[m * 3 + 2] = i2;  wgt[m * 3 + 2] = w2 * inv;
    }
}

// ---- kernel 3: fused (r11/r13 structure: full-staged wB, 72 KB, 2 blk/CU;
// gemm1 A read from x_skip f32 with inline cast).
#define LDS_STRIDE 264
#define WB_STRIDE 72
__global__ __launch_bounds__(256) void fused_kernel(const float* __restrict__ x_skip,
                                                    const ushort* __restrict__ Bt1b,
                                                    const ushort* __restrict__ Gb,
                                                    const int* __restrict__ idxw,
                                                    const float* __restrict__ wgt,
                                                    const float* __restrict__ b1,
                                                    const ushort* __restrict__ Bt2,
                                                    const float* __restrict__ b2,
                                                    float* __restrict__ out) {
    __shared__ ushort h1t[4][16 * LDS_STRIDE];     // 33792 B
    __shared__ ushort wB[256 * WB_STRIDE];         // 36864 B
    __shared__ int   sIdx[4][48];
    __shared__ float sWgt[4][48];                  // total ~72 KB -> 2 blk/CU
    int tid = threadIdx.x;
    int wave = tid >> 6, lane = tid & 63;
    int m0 = blockIdx.x * 64 + wave * 16;
    int lrow = lane & 15;
    int ko = (lane >> 4) * 8;
    int rbase = (lane >> 4) * 4;

    if (lane < 48) {
        sIdx[wave][lane] = idxw[m0 * 3 + lane];
        sWgt[wave][lane] = wgt[m0 * 3 + lane];
    }

    const ushort4* Gv = (const ushort4*)Gb;
    const int*   si = sIdx[wave];
    const float* sw = sWgt[wave];
    ushort4 g[4][3];
#define GATHER(slot, i) {                                         \
        int a0 = si[(i) * 3 + 0];                                 \
        int a1 = si[(i) * 3 + 1];                                 \
        int a2 = si[(i) * 3 + 2];                                 \
        g[slot][0] = Gv[(size_t)a0 * 64 + lane];                  \
        g[slot][1] = Gv[(size_t)a1 * 64 + lane];                  \
        g[slot][2] = Gv[(size_t)a2 * 64 + lane]; }

    GATHER(0, 0) GATHER(1, 1) GATHER(2, 2) GATHER(3, 3)

    for (int cch = tid; cch < 2048; cch += 256) {
        int n = cch >> 3, koff = (cch & 7) * 8;
        *(short8*)&wB[n * WB_STRIDE + koff] = *(const short8*)(Bt1b + n * 64 + koff);
    }
    __syncthreads();

    floatx4 acc[16];
#pragma unroll
    for (int i = 0; i < 16; ++i) acc[i] = (floatx4){0.f, 0.f, 0.f, 0.f};
    {
        const float* arow = x_skip + (size_t)(m0 + lrow) * 64 + ko;
#pragma unroll
        for (int k0 = 0; k0 < 64; k0 += 32) {
            short8 af = ld_cvt8(arow + k0);
#pragma unroll
            for (int nt = 0; nt < 16; ++nt) {
                short8 bf = *(const short8*)&wB[(nt * 16 + lrow) * WB_STRIDE + k0 + ko];
                acc[nt] = __builtin_amdgcn_mfma_f32_16x16x32_bf16(af, bf, acc[nt], 0, 0, 0);
            }
        }
    }

    ushort* ht = h1t[wave];
#pragma unroll
    for (int nt = 0; nt < 16; ++nt) {
        int n = nt * 16 + lrow;
#pragma unroll
        for (int r = 0; r < 4; ++r)
            ht[(rbase + r) * LDS_STRIDE + n] = f2bf(acc[nt][r]);
    }

    {
        float4 bv = ((const float4*)b1)[lane];
#define COMBINE(i) {                                              \
        int s = (i) & 3;                                          \
        float w0 = sw[(i) * 3 + 0], w1 = sw[(i) * 3 + 1], w2 = sw[(i) * 3 + 2]; \
        ushort4 sv = *(const ushort4*)(ht + (i) * LDS_STRIDE + 4 * lane); \
        float4 h;                                                 \
        h.x = fmaxf(bf2f(sv.x) + w0 * bf2f(g[s][0].x) + w1 * bf2f(g[s][1].x) + w2 * bf2f(g[s][2].x) + bv.x, 0.f); \
        h.y = fmaxf(bf2f(sv.y) + w0 * bf2f(g[s][0].y) + w1 * bf2f(g[s][1].y) + w2 * bf2f(g[s][2].y) + bv.y, 0.f); \
        h.z = fmaxf(bf2f(sv.z) + w0 * bf2f(g[s][0].z) + w1 * bf2f(g[s][1].z) + w2 * bf2f(g[s][2].z) + bv.z, 0.f); \
        h.w = fmaxf(bf2f(sv.w) + w0 * bf2f(g[s][0].w) + w1 * bf2f(g[s][1].w) + w2 * bf2f(g[s][2].w) + bv.w, 0.f); \
        ushort4 hp;                                               \
        hp.x = f2bf(h.x); hp.y = f2bf(h.y); hp.z = f2bf(h.z); hp.w = f2bf(h.w); \
        *(ushort4*)(ht + (i) * LDS_STRIDE + 4 * lane) = hp; }

#pragma unroll
        for (int i = 0; i < 12; ++i) { COMBINE(i); GATHER(i & 3, i + 4); }
#pragma unroll
        for (int i = 12; i < 16; ++i) { COMBINE(i); }
#undef GATHER
#undef COMBINE
    }

#pragma unroll
    for (int i = 0; i < 16; ++i) acc[i] = (floatx4){0.f, 0.f, 0.f, 0.f};
    for (int s = 0; s < 4; ++s) {
        __syncthreads();
        for (int cch = tid; cch < 2048; cch += 256) {
            int n = cch >> 3, koff = (cch & 7) * 8;
            *(short8*)&wB[n * WB_STRIDE + koff] = *(const short8*)(Bt2 + n * 256 + s * 64 + koff);
        }
        __syncthreads();
        const ushort* ar = ht + lrow * LDS_STRIDE + s * 64 + ko;
#pragma unroll
        for (int k0 = 0; k0 < 64; k0 += 32) {
            short8 af = *(const short8*)(ar + k0);
#pragma unroll
            for (int nt = 0; nt < 16; ++nt) {
                short8 bf = *(const short8*)&wB[(nt * 16 + lrow) * WB_STRIDE + k0 + ko];
                acc[nt] = __builtin_amdgcn_mfma_f32_16x16x32_bf16(af, bf, acc[nt], 0, 0, 0);
            }
        }
    }
#pragma unroll
    for (int nt = 0; nt < 16; ++nt) {
        int n = nt * 16 + lrow;
        float bv2 = b2[n];
#pragma unroll
        for (int r = 0; r < 4; ++r) {
            float v = fmaxf(acc[nt][r] + bv2, 0.f);
            out[(size_t)(m0 + rbase + r) * OUTD + n] = v;
        }
    }
}

extern "C" void kernel_launch(void* const* d_in, const int* in_sizes, int n_in,
                              void* d_out, int out_size, void* d_ws, size_t ws_size,
                              hipStream_t stream) {
    const float* x        = (const float*)d_in[0];
    const float* pos      = (const float*)d_in[1];
    const float* x_skip   = (const float*)d_in[3];
    const float* pos_skip = (const float*)d_in[4];
    const float* W1       = (const float*)d_in[6];
    const float* b1       = (const float*)d_in[7];
    const float* W2       = (const float*)d_in[8];
    const float* b2       = (const float*)d_in[9];

    char* ws = (char*)d_ws;
    size_t off = 0;
    int*    idxw = (int*)(ws + off);    off += (size_t)MTOT * 3 * 4;      //  768 KB
    float*  wgt  = (float*)(ws + off);  off += (size_t)MTOT * 3 * 4;      //  768 KB
    ushort* Gb   = (ushort*)(ws + off); off += (size_t)NCTOT * 256 * 2;   //    8 MB
    ushort* Bt1a = (ushort*)(ws + off); off += (size_t)256 * 256 * 2;     //  128 KB
    ushort* Bt1b = (ushort*)(ws + off); off += (size_t)256 * 64 * 2;      //   32 KB
    ushort* Bt2  = (ushort*)(ws + off); off += (size_t)256 * 256 * 2;     //  128 KB
    float* out = (float*)d_out;

    prep_w<<<36, 256, 0, stream>>>(W1, W2, Bt1a, Bt1b, Bt2);
    knn_gemm<<<TAIL_BASE + TAIL_BLOCKS, 512, 0, stream>>>(
        pos, pos_skip, idxw, wgt, x, Bt1a, Gb, out);
    fused_kernel<<<MTOT / 64, 256, 0, stream>>>(x_skip, Bt1b, Gb, idxw, wgt, b1, Bt2, b2, out);
}